// Round 13
// baseline (330.319 us; speedup 1.0000x reference)
//
#include <hip/hip_runtime.h>
#include <math.h>

#define NN 100000
#define NP 100032   // 64 * 1563 (padded node count)
#define NE 2000000
#define FIN 32
#define H 32
#define NC 40

#define NBK 196      // coarse buckets: dst>>9 (512 nodes each)
#define BSH 9
#define CAP 11264    // per-bucket capacity: mean 10240 + ~10 sigma
#define EPT 8
#define EPB (256 * EPT)  // 2048 edges per block -> 977 blocks (occupancy, round-13)

typedef _Float16 half_t;
typedef __attribute__((ext_vector_type(8))) _Float16 half8;
typedef __attribute__((ext_vector_type(4))) float f32x4;

__device__ __forceinline__ float sigm_(float x) {
    return 1.0f / (1.0f + __expf(-x));
}
__device__ __forceinline__ float tanh_(float x) {
    x = fminf(fmaxf(x, -20.0f), 20.0f);
    float e = __expf(2.0f * x);
    return (e - 1.0f) / (e + 1.0f);
}

// ---------- phase A: coarse-bucket scatter; per-edge atomics are LDS-only ----------
// dst cached in registers across phases; EPT=8 for ~4 blocks/CU.
__global__ __launch_bounds__(256) void kA_bucket(const int* __restrict__ ei,
                                                 const float* __restrict__ ew,
                                                 int* __restrict__ gcur,
                                                 int2* __restrict__ rec) {
    __shared__ int cnt[NBK], base[NBK];
    int tid = threadIdx.x;
    for (int i = tid; i < NBK; i += 256) cnt[i] = 0;
    __syncthreads();
    int e0 = blockIdx.x * EPB;
    int dcache[EPT];
#pragma unroll
    for (int i = 0; i < EPT; ++i) {
        int e = e0 + i * 256 + tid;
        dcache[i] = (e < NE) ? ei[NE + e] : -1;
        if (e < NE) atomicAdd(&cnt[dcache[i] >> BSH], 1);
    }
    __syncthreads();
    for (int i = tid; i < NBK; i += 256) {
        base[i] = atomicAdd(&gcur[i], cnt[i]);  // one global atomic per (block,bucket)
        cnt[i] = 0;
    }
    __syncthreads();
#pragma unroll
    for (int i = 0; i < EPT; ++i) {
        int e = e0 + i * 256 + tid;
        if (e < NE) {
            int d = dcache[i], s = ei[e];
            int b = d >> BSH;
            int r = atomicAdd(&cnt[b], 1);
            int pos = base[b] + r;
            if (pos < CAP)  // statistically impossible overflow guard
                rec[(size_t)b * CAP + pos] =
                    make_int2(s | ((d & 511) << 17), __float_as_int(ew[e]));
        }
    }
}

// ---------- phase B: per-bucket local counting sort (LDS hist + scan + rank) ----------
__global__ __launch_bounds__(256) void kB_sort(const int* __restrict__ gcur,
                                               const int2* __restrict__ rec,
                                               int2* __restrict__ evs,
                                               int* __restrict__ ofs,
                                               int* __restrict__ ocn) {
    __shared__ int hist[512], lofs[512], ssc[256];
    int tid = threadIdx.x, b = blockIdx.x;
    int nb0 = b << BSH;
    int nnodes = min(512, NN - nb0);
    int cntb = min(gcur[b], CAP);
    hist[tid] = 0;
    hist[tid + 256] = 0;
    __syncthreads();
    const int2* rb = rec + (size_t)b * CAP;
    for (int i = tid; i < cntb; i += 256)
        atomicAdd(&hist[(rb[i].x >> 17) & 511], 1);
    __syncthreads();
    int ps = hist[2 * tid] + hist[2 * tid + 1];
    ssc[tid] = ps;
    __syncthreads();
    for (int off = 1; off < 256; off <<= 1) {
        int v = (tid >= off) ? ssc[tid - off] : 0;
        __syncthreads();
        ssc[tid] += v;
        __syncthreads();
    }
    int ex = ssc[tid] - ps;  // exclusive over pairs
    lofs[2 * tid] = ex;
    lofs[2 * tid + 1] = ex + hist[2 * tid];
    __syncthreads();
    for (int l = tid; l < nnodes; l += 256) {  // per-node CSR meta (coalesced)
        ofs[nb0 + l] = b * CAP + lofs[l];
        ocn[nb0 + l] = hist[l];
    }
    hist[tid] = 0;  // same thread zeroes exactly the bins it read above
    hist[tid + 256] = 0;
    __syncthreads();
    int2* eb = evs + (size_t)b * CAP;
    for (int i = tid; i < cntb; i += 256) {
        int2 r = rb[i];
        int dl = (r.x >> 17) & 511;
        int rk = atomicAdd(&hist[dl], 1);
        eb[lofs[dl] + rk] = make_int2(r.x & 0x1FFFF, r.y);
    }
}

// ---------- stage 1 of layer-2 weight fold: M2[u][col] = sum_t W2m[u,t] * wih2[col,t] ----------
__global__ __launch_bounds__(256) void k_wpre(const float* __restrict__ W2m,
                                              const float* __restrict__ wih2,
                                              float* __restrict__ M2) {
    int i = blockIdx.x * 256 + threadIdx.x;
    if (i >= NC * 3 * NC) return;
    int u = i / (3 * NC), col = i % (3 * NC);
    float acc = 0.f;
#pragma unroll
    for (int t = 0; t < NC; ++t) acc += W2m[u * NC + t] * wih2[col * NC + t];
    M2[i] = acc;
}

// ---------- build MFMA B-fragment-linear fp16 weight tables ----------
// Layer1: cols 0..31 r(fused K=64), 32..63 z(fused), 64..95 i_n(k<32), 96..127 h_n(k>=32)
// Layer2: gate blocks of 48 cols (40 used); K padded to 96.
__global__ __launch_bounds__(256) void k_wc(const float* __restrict__ W1m,
                                            const float* __restrict__ wih1,
                                            const float* __restrict__ W2p,
                                            const float* __restrict__ M2,
                                            const float* __restrict__ whh1,
                                            const float* __restrict__ whh2,
                                            half_t* __restrict__ W1sw,
                                            half_t* __restrict__ W2sw) {
    int i = blockIdx.x * 256 + threadIdx.x;
    if (i < 8192) {
        int j = i & 7, lane = (i >> 3) & 63, ct = (i >> 9) & 7, s = i >> 12;
        int k = s * 32 + (lane >> 4) * 8 + j;
        int col = ct * 16 + (lane & 15);
        int g = col >> 5, jj = col & 31;
        float v = 0.f;
        if (g <= 2) {
            if (k < 32) {  // input side (agg): fold W1m @ wih1^T
                float acc = 0.f;
#pragma unroll
                for (int t = 0; t < H; ++t) acc += W1m[k * H + t] * wih1[(g * H + jj) * H + t];
                v = acc;
            } else if (g < 2) {  // r,z hidden side
                v = whh1[(g * H + jj) * H + (k - 32)];
            }                     // g==2 (i_n), k>=32 -> 0
        } else {                  // g==3 (h_n): hidden side only
            if (k >= 32) v = whh1[(2 * H + jj) * H + (k - 32)];
        }
        W1sw[i] = (half_t)v;
    } else if (i < 8192 + 18432) {
        int i2 = i - 8192;
        int j = i2 & 7, lane = (i2 >> 3) & 63;
        int tt = i2 >> 9;  // 0..35
        int ct = tt % 12, s = tt / 12;
        int k = s * 32 + (lane >> 4) * 8 + j;  // 0..95
        int col = ct * 16 + (lane & 15);       // 0..191
        int g = col / 48, jj = col % 48;
        float v = 0.f;
        if (jj < NC) {
            if (g <= 2) {
                if (k < 32) {  // input side (aggX): W2p @ M2 (stage-1 precomputed)
                    float acc = 0.f;
#pragma unroll
                    for (int u = 0; u < NC; ++u)
                        acc += W2p[k * NC + u] * M2[u * 3 * NC + g * NC + jj];
                    v = acc;
                } else if (k < 72 && g < 2) {  // r,z hidden side
                    v = whh2[(g * NC + jj) * NC + (k - 32)];
                }
            } else {  // g==3 (h_n)
                if (k >= 32 && k < 72) v = whh2[(2 * NC + jj) * NC + (k - 32)];
            }
        }
        W2sw[i2] = (half_t)v;
    }
}

// ---------- K1: h1 = x @ W1p -> fp16 into Xc1 cols 32..63 (stride 64) ----------
__global__ __launch_bounds__(256) void k1_proj(const float* __restrict__ x,
                                               const float* __restrict__ Wp,
                                               half_t* __restrict__ Xc1) {
    __shared__ float sWp[FIN * H];
    __shared__ float sx[8][FIN];
    int tid = threadIdx.x;
    for (int i = tid; i < FIN * H; i += 256) sWp[i] = Wp[i];
    int nb = blockIdx.x * 8;
    int nl = tid >> 5, j = tid & 31;
    int n = nb + nl;
    if (n < NN) sx[nl][j] = x[(size_t)n * FIN + j];
    __syncthreads();
    float acc = 0.f;
#pragma unroll
    for (int k = 0; k < FIN; ++k) acc += sx[nl][k] * sWp[k * H + j];
    if (n < NN) Xc1[(size_t)n * 64 + 32 + j] = (half_t)acc;
}

// ---------- K4: h2 = hrelu @ W2p -> fp16 into Xc2 cols 32..71 (stride 96); zero pad 72..95 ----------
__global__ __launch_bounds__(320) void k4_proj2(const half_t* __restrict__ Hh,
                                                const float* __restrict__ Wp,
                                                half_t* __restrict__ Xc2) {
    __shared__ float sWp[FIN * NC];
    __shared__ float shn[8][FIN];
    int tid = threadIdx.x;
    for (int i = tid; i < FIN * NC; i += 320) sWp[i] = Wp[i];
    int nb = blockIdx.x * 8;
    if (tid < 256) {
        int r = tid >> 5, c = tid & 31;
        shn[r][c] = (float)Hh[(size_t)(nb + r) * 32 + c];
    }
    // zero K-pad cols 72..95: this region overlays stale CSR-build scratch whose
    // bit patterns can be fp16-NaN, and MFMA 0*NaN = NaN (round-7 failure).
    if (tid < 192) {
        int r = tid / 24, c = tid % 24;
        Xc2[(size_t)(nb + r) * 96 + 72 + c] = (half_t)0.f;
    }
    __syncthreads();
    int nl = tid / NC, j = tid % NC;
    int n = nb + nl;
    float acc = 0.f;
#pragma unroll
    for (int k = 0; k < FIN; ++k) acc += shn[nl][k] * sWp[k * NC + j];
    if (n < NN) Xc2[(size_t)n * 96 + 32 + j] = (half_t)acc;
}

// ---------- aggregation: fp16 gather, fp32 accum, 4-way edge unroll for MLP ----------
__global__ __launch_bounds__(256) void k_aggh(const int* __restrict__ ofs,
                                              const int* __restrict__ ocn,
                                              const int2* __restrict__ evs,
                                              const half_t* __restrict__ src, int sstr8,
                                              half_t* __restrict__ dst, int dstr) {
    int idx = blockIdx.x * 256 + threadIdx.x;
    int n = idx >> 2, q = idx & 3;
    if (n >= NN) return;
    const half8* s8 = (const half8*)src;
    int s0 = ofs[n], c = ocn[n];
    int e1 = s0 + c;
    float acc[8] = {0.f, 0.f, 0.f, 0.f, 0.f, 0.f, 0.f, 0.f};
    int e = s0;
    for (; e + 4 <= e1; e += 4) {
        int2 r0 = evs[e], r1 = evs[e + 1], r2 = evs[e + 2], r3 = evs[e + 3];
        half8 h0 = s8[(size_t)(r0.x & 0x1FFFF) * sstr8 + q];
        half8 h1 = s8[(size_t)(r1.x & 0x1FFFF) * sstr8 + q];
        half8 h2 = s8[(size_t)(r2.x & 0x1FFFF) * sstr8 + q];
        half8 h3 = s8[(size_t)(r3.x & 0x1FFFF) * sstr8 + q];
        float w0 = __int_as_float(r0.y), w1 = __int_as_float(r1.y);
        float w2 = __int_as_float(r2.y), w3 = __int_as_float(r3.y);
#pragma unroll
        for (int t = 0; t < 8; ++t) {
            acc[t] += w0 * (float)h0[t];
            acc[t] += w1 * (float)h1[t];
            acc[t] += w2 * (float)h2[t];
            acc[t] += w3 * (float)h3[t];
        }
    }
    for (; e < e1; ++e) {
        int2 r = evs[e];
        float w = __int_as_float(r.y);
        half8 hv = s8[(size_t)(r.x & 0x1FFFF) * sstr8 + q];
#pragma unroll
        for (int t = 0; t < 8; ++t) acc[t] += w * (float)hv[t];
    }
    half8 o;
#pragma unroll
    for (int t = 0; t < 8; ++t) o[t] = (half_t)acc[t];
    *(half8*)(dst + (size_t)n * dstr + q * 8) = o;
}

// ---------- K3: GRU layer1 + relu via MFMA. 4 waves x 16 nodes, no LDS ----------
__global__ __launch_bounds__(256) void k3m(const half_t* __restrict__ Xc1,
                                           const half8* __restrict__ W1sw,
                                           const float* __restrict__ bih,
                                           const float* __restrict__ bhh,
                                           half_t* __restrict__ Hh) {
    int tid = threadIdx.x;
    int wave = tid >> 6, lane = tid & 63;
    int m16 = lane & 15, q = lane >> 4;
    int nb = blockIdx.x * 64 + wave * 16;
    const half8* xr = (const half8*)(Xc1 + (size_t)(nb + m16) * 64);
    half8 a0 = xr[q];      // k = q*8..q*8+7
    half8 a1 = xr[4 + q];  // k = 32+q*8..
    f32x4 acc[8];
#pragma unroll
    for (int ct = 0; ct < 8; ++ct) acc[ct] = (f32x4){0.f, 0.f, 0.f, 0.f};
#pragma unroll
    for (int ct = 0; ct < 8; ++ct) {
        acc[ct] = __builtin_amdgcn_mfma_f32_16x16x32_f16(a0, W1sw[ct * 64 + lane], acc[ct], 0, 0, 0);
        acc[ct] = __builtin_amdgcn_mfma_f32_16x16x32_f16(a1, W1sw[(8 + ct) * 64 + lane], acc[ct], 0, 0, 0);
    }
#pragma unroll
    for (int ct = 0; ct < 2; ++ct) {
        int j = ct * 16 + m16;
        float br = bih[j] + bhh[j];
        float bz = bih[H + j] + bhh[H + j];
        float bi = bih[2 * H + j], bh = bhh[2 * H + j];
#pragma unroll
        for (int m = 0; m < 4; ++m) {
            int node = nb + q * 4 + m;  // C/D: row = quad*4 + reg, col = lane&15
            float r = sigm_(acc[ct][m] + br);
            float z = sigm_(acc[2 + ct][m] + bz);
            float ng = tanh_(acc[4 + ct][m] + bi + r * (acc[6 + ct][m] + bh));
            float hj = (float)Xc1[(size_t)node * 64 + 32 + j];
            float o = fmaxf((1.f - z) * ng + z * hj, 0.f);
            if (node < NN) Hh[(size_t)node * 32 + j] = (half_t)o;
        }
    }
}

// ---------- K6: GRU layer2 + log_softmax via MFMA + shfl reduce, no LDS ----------
__global__ __launch_bounds__(256) void k6m(const half_t* __restrict__ Xc2,
                                           const half8* __restrict__ W2sw,
                                           const float* __restrict__ bih,
                                           const float* __restrict__ bhh,
                                           float* __restrict__ out) {
    int tid = threadIdx.x;
    int wave = tid >> 6, lane = tid & 63;
    int m16 = lane & 15, q = lane >> 4;
    int nb = blockIdx.x * 64 + wave * 16;
    const half8* xr = (const half8*)(Xc2 + (size_t)(nb + m16) * 96);
    half8 a0 = xr[q], a1 = xr[4 + q], a2 = xr[8 + q];
    f32x4 acc[12];
#pragma unroll
    for (int ct = 0; ct < 12; ++ct) acc[ct] = (f32x4){0.f, 0.f, 0.f, 0.f};
#pragma unroll
    for (int ct = 0; ct < 12; ++ct) {
        acc[ct] = __builtin_amdgcn_mfma_f32_16x16x32_f16(a0, W2sw[ct * 64 + lane], acc[ct], 0, 0, 0);
        acc[ct] = __builtin_amdgcn_mfma_f32_16x16x32_f16(a1, W2sw[(12 + ct) * 64 + lane], acc[ct], 0, 0, 0);
        acc[ct] = __builtin_amdgcn_mfma_f32_16x16x32_f16(a2, W2sw[(24 + ct) * 64 + lane], acc[ct], 0, 0, 0);
    }
    float v[3][4];
#pragma unroll
    for (int ct = 0; ct < 3; ++ct) {
        int j = ct * 16 + m16;
        int jc = (j < NC) ? j : (NC - 1);  // clamp (lanes with j>=40 produce unused values)
        float br = bih[jc] + bhh[jc];
        float bz = bih[NC + jc] + bhh[NC + jc];
        float bi = bih[2 * NC + jc], bh = bhh[2 * NC + jc];
#pragma unroll
        for (int m = 0; m < 4; ++m) {
            int node = nb + q * 4 + m;
            float r = sigm_(acc[ct][m] + br);
            float z = sigm_(acc[3 + ct][m] + bz);
            float ng = tanh_(acc[6 + ct][m] + bi + r * (acc[9 + ct][m] + bh));
            float hj = (float)Xc2[(size_t)node * 96 + 32 + jc];
            v[ct][m] = (1.f - z) * ng + z * hj;
        }
    }
    bool v2ok = (m16 < 8);  // ct=2 covers j=32..39 only for m16<8
#pragma unroll
    for (int m = 0; m < 4; ++m) {
        float mx = fmaxf(v[0][m], v[1][m]);
        if (v2ok) mx = fmaxf(mx, v[2][m]);
#pragma unroll
        for (int d = 1; d < 16; d <<= 1) mx = fmaxf(mx, __shfl_xor(mx, d));
        float se = __expf(v[0][m] - mx) + __expf(v[1][m] - mx) +
                   (v2ok ? __expf(v[2][m] - mx) : 0.f);
#pragma unroll
        for (int d = 1; d < 16; d <<= 1) se += __shfl_xor(se, d);
        float ls = mx + __logf(se);
        int node = nb + q * 4 + m;
        if (node < NN) {
            out[(size_t)node * NC + m16] = v[0][m] - ls;
            out[(size_t)node * NC + 16 + m16] = v[1][m] - ls;
            if (v2ok) out[(size_t)node * NC + 32 + m16] = v[2][m] - ls;
        }
    }
}

extern "C" void kernel_launch(void* const* d_in, const int* in_sizes, int n_in,
                              void* d_out, int out_size, void* d_ws, size_t ws_size,
                              hipStream_t stream) {
    const float* x = (const float*)d_in[0];
    const int* ei = (const int*)d_in[1];
    const float* ew = (const float*)d_in[2];
    const float* W1p = (const float*)d_in[3];
    const float* W1m = (const float*)d_in[4];
    const float* g1wih = (const float*)d_in[5];
    const float* g1whh = (const float*)d_in[6];
    const float* g1bih = (const float*)d_in[7];
    const float* g1bhh = (const float*)d_in[8];
    const float* W2p = (const float*)d_in[9];
    const float* W2m = (const float*)d_in[10];
    const float* g2wih = (const float*)d_in[11];
    const float* g2whh = (const float*)d_in[12];
    const float* g2bih = (const float*)d_in[13];
    const float* g2bhh = (const float*)d_in[14];
    float* ws = (float*)d_ws;

    // workspace layout (float indices), ~44 MB total (round-8 proven layout):
    half_t* Xc = (half_t*)ws;                 // [NP][64] layer1 / [NP][96] layer2 fp16 activations (4,801,536 f)
    half_t* Hh = (half_t*)(ws + 4801536);     // [NP][32] fp16 hrelu gather table (1,600,512 f)
    int2* rec = (int2*)ws;                    // CSR-build scratch (4,415,488 f) — dead before k1, overlays Xc
    int2* evs = (int2*)(ws + 6402048);        // 196*CAP sorted records (4,415,488 f)
    int* ofs = (int*)(ws + 10817536);         // 100,000
    int* ocn = (int*)(ws + 10917536);         // 100,000
    int* gcur = (int*)(ws + 11017536);        // 196 (+pad)
    half_t* W1sw = (half_t*)(ws + 11017792);  // 8,192 halves (4,096 f)
    half_t* W2sw = W1sw + 8192;               // 18,432 halves (9,216 f)
    float* M2 = ws + 11031104;                // 4,800 f: stage-1 fold W2m @ wih2^T
    float* out = (float*)d_out;

    // ---- CSR build (shared by both layers) ----
    hipMemsetAsync(gcur, 0, NBK * sizeof(int), stream);
    kA_bucket<<<(NE + EPB - 1) / EPB, 256, 0, stream>>>(ei, ew, gcur, rec);
    kB_sort<<<NBK, 256, 0, stream>>>(gcur, rec, evs, ofs, ocn);
    k_wpre<<<(NC * 3 * NC + 255) / 256, 256, 0, stream>>>(W2m, g2wih, M2);
    k_wc<<<(8192 + 18432 + 255) / 256, 256, 0, stream>>>(
        W1m, g1wih, W2p, M2, g1whh, g2whh, W1sw, W2sw);

    // ---- layer 1 ----
    k1_proj<<<NN / 8, 256, 0, stream>>>(x, W1p, Xc);
    k_aggh<<<(NN * 4 + 255) / 256, 256, 0, stream>>>(ofs, ocn, evs, Xc + 32, 8, Xc, 64);
    k3m<<<NP / 64, 256, 0, stream>>>(Xc, (const half8*)W1sw, g1bih, g1bhh, Hh);

    // ---- layer 2 ----
    k4_proj2<<<NN / 8, 320, 0, stream>>>(Hh, W2p, Xc);
    k_aggh<<<(NN * 4 + 255) / 256, 256, 0, stream>>>(ofs, ocn, evs, Hh, 4, Xc, 96);
    k6m<<<NP / 64, 256, 0, stream>>>(Xc, (const half8*)W2sw, g2bih, g2bhh, out);
}

// Round 14
// 306.602 us; speedup vs baseline: 1.0774x; 1.0774x over previous
//
#include <hip/hip_runtime.h>
#include <math.h>

#define NN 100000
#define NP 100032   // 64 * 1563 (padded node count)
#define NE 2000000
#define FIN 32
#define H 32
#define NC 40

#define NBK 196      // coarse buckets: dst>>9 (512 nodes each)
#define BSH 9
#define CAP 11264    // per-bucket capacity: mean 10240 + ~10 sigma
#define EPT 16
#define EPB (256 * EPT)  // 4096 edges per block (round-13 EPT=8 regressed: shorter runs -> worse write amp)

typedef _Float16 half_t;
typedef __attribute__((ext_vector_type(8))) _Float16 half8;
typedef __attribute__((ext_vector_type(4))) float f32x4;

__device__ __forceinline__ float sigm_(float x) {
    return 1.0f / (1.0f + __expf(-x));
}
__device__ __forceinline__ float tanh_(float x) {
    x = fminf(fmaxf(x, -20.0f), 20.0f);
    float e = __expf(2.0f * x);
    return (e - 1.0f) / (e + 1.0f);
}

// ---------- phase A: coarse-bucket scatter with LDS staging ----------
// Records are bucket-sorted in LDS, then written as coalesced per-bucket runs
// (round-13 lesson: 2M scattered 8B stores = 2M write transactions was the limiter).
__global__ __launch_bounds__(256) void kA_bucket(const int* __restrict__ ei,
                                                 const float* __restrict__ ew,
                                                 int* __restrict__ gcur,
                                                 long long* __restrict__ rec) {
    __shared__ long long recs[EPB];   // 32 KB bucket-sorted records
    __shared__ int gdst[EPB];         // 16 KB absolute global slot per record
    __shared__ int cnt[NBK], base[NBK], sofs[NBK];
    __shared__ int ssc[256];
    int tid = threadIdx.x;
    for (int i = tid; i < NBK; i += 256) cnt[i] = 0;
    __syncthreads();
    int e0 = blockIdx.x * EPB;
    int dcache[EPT];
#pragma unroll
    for (int i = 0; i < EPT; ++i) {
        int e = e0 + i * 256 + tid;
        dcache[i] = (e < NE) ? ei[NE + e] : -1;
        if (e < NE) atomicAdd(&cnt[dcache[i] >> BSH], 1);
    }
    __syncthreads();
    // exclusive scan of cnt -> sofs (LDS slot base per bucket), and global reserve
    int cv = (tid < NBK) ? cnt[tid] : 0;
    ssc[tid] = cv;
    __syncthreads();
    for (int off = 1; off < 256; off <<= 1) {
        int v = (tid >= off) ? ssc[tid - off] : 0;
        __syncthreads();
        ssc[tid] += v;
        __syncthreads();
    }
    if (tid < NBK) {
        sofs[tid] = ssc[tid] - cv;
        base[tid] = atomicAdd(&gcur[tid], cv);  // one global atomic per (block,bucket)
        cnt[tid] = 0;                           // reuse as rank cursor
    }
    __syncthreads();
#pragma unroll
    for (int i = 0; i < EPT; ++i) {
        int e = e0 + i * 256 + tid;
        if (e < NE) {
            int d = dcache[i], s = ei[e];
            int b = d >> BSH;
            int r = atomicAdd(&cnt[b], 1);
            int slot = sofs[b] + r;
            int pos = base[b] + r;
            int lo = s | ((d & 511) << 17);
            recs[slot] = (long long)(unsigned)lo |
                         ((long long)__float_as_int(ew[e]) << 32);
            gdst[slot] = (pos < CAP) ? (b * CAP + pos) : -1;  // overflow guard
        }
    }
    __syncthreads();
    int nrec = min(EPB, NE - e0);
    for (int i = tid; i < nrec; i += 256) {  // consecutive slots -> consecutive global addrs
        int gd = gdst[i];
        if (gd >= 0) rec[gd] = recs[i];
    }
}

// ---------- phase B: per-bucket local counting sort (LDS hist + scan + rank) ----------
__global__ __launch_bounds__(256) void kB_sort(const int* __restrict__ gcur,
                                               const int2* __restrict__ rec,
                                               int2* __restrict__ evs,
                                               int* __restrict__ ofs,
                                               int* __restrict__ ocn) {
    __shared__ int hist[512], lofs[512], ssc[256];
    int tid = threadIdx.x, b = blockIdx.x;
    int nb0 = b << BSH;
    int nnodes = min(512, NN - nb0);
    int cntb = min(gcur[b], CAP);
    hist[tid] = 0;
    hist[tid + 256] = 0;
    __syncthreads();
    const int2* rb = rec + (size_t)b * CAP;
    for (int i = tid; i < cntb; i += 256)
        atomicAdd(&hist[(rb[i].x >> 17) & 511], 1);
    __syncthreads();
    int ps = hist[2 * tid] + hist[2 * tid + 1];
    ssc[tid] = ps;
    __syncthreads();
    for (int off = 1; off < 256; off <<= 1) {
        int v = (tid >= off) ? ssc[tid - off] : 0;
        __syncthreads();
        ssc[tid] += v;
        __syncthreads();
    }
    int ex = ssc[tid] - ps;  // exclusive over pairs
    lofs[2 * tid] = ex;
    lofs[2 * tid + 1] = ex + hist[2 * tid];
    __syncthreads();
    for (int l = tid; l < nnodes; l += 256) {  // per-node CSR meta (coalesced)
        ofs[nb0 + l] = b * CAP + lofs[l];
        ocn[nb0 + l] = hist[l];
    }
    hist[tid] = 0;  // same thread zeroes exactly the bins it read above
    hist[tid + 256] = 0;
    __syncthreads();
    int2* eb = evs + (size_t)b * CAP;
    for (int i = tid; i < cntb; i += 256) {
        int2 r = rb[i];
        int dl = (r.x >> 17) & 511;
        int rk = atomicAdd(&hist[dl], 1);
        eb[lofs[dl] + rk] = make_int2(r.x & 0x1FFFF, r.y);
    }
}

// ---------- stage 1 of layer-2 weight fold: M2[u][col] = sum_t W2m[u,t] * wih2[col,t] ----------
__global__ __launch_bounds__(256) void k_wpre(const float* __restrict__ W2m,
                                              const float* __restrict__ wih2,
                                              float* __restrict__ M2) {
    int i = blockIdx.x * 256 + threadIdx.x;
    if (i >= NC * 3 * NC) return;
    int u = i / (3 * NC), col = i % (3 * NC);
    float acc = 0.f;
#pragma unroll
    for (int t = 0; t < NC; ++t) acc += W2m[u * NC + t] * wih2[col * NC + t];
    M2[i] = acc;
}

// ---------- build MFMA B-fragment-linear fp16 weight tables ----------
// Layer1: cols 0..31 r(fused K=64), 32..63 z(fused), 64..95 i_n(k<32), 96..127 h_n(k>=32)
// Layer2: gate blocks of 48 cols (40 used); K padded to 96.
__global__ __launch_bounds__(256) void k_wc(const float* __restrict__ W1m,
                                            const float* __restrict__ wih1,
                                            const float* __restrict__ W2p,
                                            const float* __restrict__ M2,
                                            const float* __restrict__ whh1,
                                            const float* __restrict__ whh2,
                                            half_t* __restrict__ W1sw,
                                            half_t* __restrict__ W2sw) {
    int i = blockIdx.x * 256 + threadIdx.x;
    if (i < 8192) {
        int j = i & 7, lane = (i >> 3) & 63, ct = (i >> 9) & 7, s = i >> 12;
        int k = s * 32 + (lane >> 4) * 8 + j;
        int col = ct * 16 + (lane & 15);
        int g = col >> 5, jj = col & 31;
        float v = 0.f;
        if (g <= 2) {
            if (k < 32) {  // input side (agg): fold W1m @ wih1^T
                float acc = 0.f;
#pragma unroll
                for (int t = 0; t < H; ++t) acc += W1m[k * H + t] * wih1[(g * H + jj) * H + t];
                v = acc;
            } else if (g < 2) {  // r,z hidden side
                v = whh1[(g * H + jj) * H + (k - 32)];
            }                     // g==2 (i_n), k>=32 -> 0
        } else {                  // g==3 (h_n): hidden side only
            if (k >= 32) v = whh1[(2 * H + jj) * H + (k - 32)];
        }
        W1sw[i] = (half_t)v;
    } else if (i < 8192 + 18432) {
        int i2 = i - 8192;
        int j = i2 & 7, lane = (i2 >> 3) & 63;
        int tt = i2 >> 9;  // 0..35
        int ct = tt % 12, s = tt / 12;
        int k = s * 32 + (lane >> 4) * 8 + j;  // 0..95
        int col = ct * 16 + (lane & 15);       // 0..191
        int g = col / 48, jj = col % 48;
        float v = 0.f;
        if (jj < NC) {
            if (g <= 2) {
                if (k < 32) {  // input side (aggX): W2p @ M2 (stage-1 precomputed)
                    float acc = 0.f;
#pragma unroll
                    for (int u = 0; u < NC; ++u)
                        acc += W2p[k * NC + u] * M2[u * 3 * NC + g * NC + jj];
                    v = acc;
                } else if (k < 72 && g < 2) {  // r,z hidden side
                    v = whh2[(g * NC + jj) * NC + (k - 32)];
                }
            } else {  // g==3 (h_n)
                if (k >= 32 && k < 72) v = whh2[(2 * NC + jj) * NC + (k - 32)];
            }
        }
        W2sw[i2] = (half_t)v;
    }
}

// ---------- K1: h1 = x @ W1p -> fp16 into Xc1 cols 32..63 (stride 64) ----------
__global__ __launch_bounds__(256) void k1_proj(const float* __restrict__ x,
                                               const float* __restrict__ Wp,
                                               half_t* __restrict__ Xc1) {
    __shared__ float sWp[FIN * H];
    __shared__ float sx[8][FIN];
    int tid = threadIdx.x;
    for (int i = tid; i < FIN * H; i += 256) sWp[i] = Wp[i];
    int nb = blockIdx.x * 8;
    int nl = tid >> 5, j = tid & 31;
    int n = nb + nl;
    if (n < NN) sx[nl][j] = x[(size_t)n * FIN + j];
    __syncthreads();
    float acc = 0.f;
#pragma unroll
    for (int k = 0; k < FIN; ++k) acc += sx[nl][k] * sWp[k * H + j];
    if (n < NN) Xc1[(size_t)n * 64 + 32 + j] = (half_t)acc;
}

// ---------- K4: h2 = hrelu @ W2p -> fp16 into Xc2 cols 32..71 (stride 96); zero pad 72..95 ----------
__global__ __launch_bounds__(320) void k4_proj2(const half_t* __restrict__ Hh,
                                                const float* __restrict__ Wp,
                                                half_t* __restrict__ Xc2) {
    __shared__ float sWp[FIN * NC];
    __shared__ float shn[8][FIN];
    int tid = threadIdx.x;
    for (int i = tid; i < FIN * NC; i += 320) sWp[i] = Wp[i];
    int nb = blockIdx.x * 8;
    if (tid < 256) {
        int r = tid >> 5, c = tid & 31;
        shn[r][c] = (float)Hh[(size_t)(nb + r) * 32 + c];
    }
    // zero K-pad cols 72..95: this region overlays stale CSR-build scratch whose
    // bit patterns can be fp16-NaN, and MFMA 0*NaN = NaN (round-7 failure).
    if (tid < 192) {
        int r = tid / 24, c = tid % 24;
        Xc2[(size_t)(nb + r) * 96 + 72 + c] = (half_t)0.f;
    }
    __syncthreads();
    int nl = tid / NC, j = tid % NC;
    int n = nb + nl;
    float acc = 0.f;
#pragma unroll
    for (int k = 0; k < FIN; ++k) acc += shn[nl][k] * sWp[k * NC + j];
    if (n < NN) Xc2[(size_t)n * 96 + 32 + j] = (half_t)acc;
}

// ---------- aggregation: fp16 gather, fp32 accum, 4-way edge unroll for MLP ----------
__global__ __launch_bounds__(256) void k_aggh(const int* __restrict__ ofs,
                                              const int* __restrict__ ocn,
                                              const int2* __restrict__ evs,
                                              const half_t* __restrict__ src, int sstr8,
                                              half_t* __restrict__ dst, int dstr) {
    int idx = blockIdx.x * 256 + threadIdx.x;
    int n = idx >> 2, q = idx & 3;
    if (n >= NN) return;
    const half8* s8 = (const half8*)src;
    int s0 = ofs[n], c = ocn[n];
    int e1 = s0 + c;
    float acc[8] = {0.f, 0.f, 0.f, 0.f, 0.f, 0.f, 0.f, 0.f};
    int e = s0;
    for (; e + 4 <= e1; e += 4) {
        int2 r0 = evs[e], r1 = evs[e + 1], r2 = evs[e + 2], r3 = evs[e + 3];
        half8 h0 = s8[(size_t)(r0.x & 0x1FFFF) * sstr8 + q];
        half8 h1 = s8[(size_t)(r1.x & 0x1FFFF) * sstr8 + q];
        half8 h2 = s8[(size_t)(r2.x & 0x1FFFF) * sstr8 + q];
        half8 h3 = s8[(size_t)(r3.x & 0x1FFFF) * sstr8 + q];
        float w0 = __int_as_float(r0.y), w1 = __int_as_float(r1.y);
        float w2 = __int_as_float(r2.y), w3 = __int_as_float(r3.y);
#pragma unroll
        for (int t = 0; t < 8; ++t) {
            acc[t] += w0 * (float)h0[t];
            acc[t] += w1 * (float)h1[t];
            acc[t] += w2 * (float)h2[t];
            acc[t] += w3 * (float)h3[t];
        }
    }
    for (; e < e1; ++e) {
        int2 r = evs[e];
        float w = __int_as_float(r.y);
        half8 hv = s8[(size_t)(r.x & 0x1FFFF) * sstr8 + q];
#pragma unroll
        for (int t = 0; t < 8; ++t) acc[t] += w * (float)hv[t];
    }
    half8 o;
#pragma unroll
    for (int t = 0; t < 8; ++t) o[t] = (half_t)acc[t];
    *(half8*)(dst + (size_t)n * dstr + q * 8) = o;
}

// ---------- K3: GRU layer1 + relu via MFMA. 4 waves x 16 nodes, no LDS ----------
__global__ __launch_bounds__(256) void k3m(const half_t* __restrict__ Xc1,
                                           const half8* __restrict__ W1sw,
                                           const float* __restrict__ bih,
                                           const float* __restrict__ bhh,
                                           half_t* __restrict__ Hh) {
    int tid = threadIdx.x;
    int wave = tid >> 6, lane = tid & 63;
    int m16 = lane & 15, q = lane >> 4;
    int nb = blockIdx.x * 64 + wave * 16;
    const half8* xr = (const half8*)(Xc1 + (size_t)(nb + m16) * 64);
    half8 a0 = xr[q];      // k = q*8..q*8+7
    half8 a1 = xr[4 + q];  // k = 32+q*8..
    f32x4 acc[8];
#pragma unroll
    for (int ct = 0; ct < 8; ++ct) acc[ct] = (f32x4){0.f, 0.f, 0.f, 0.f};
#pragma unroll
    for (int ct = 0; ct < 8; ++ct) {
        acc[ct] = __builtin_amdgcn_mfma_f32_16x16x32_f16(a0, W1sw[ct * 64 + lane], acc[ct], 0, 0, 0);
        acc[ct] = __builtin_amdgcn_mfma_f32_16x16x32_f16(a1, W1sw[(8 + ct) * 64 + lane], acc[ct], 0, 0, 0);
    }
#pragma unroll
    for (int ct = 0; ct < 2; ++ct) {
        int j = ct * 16 + m16;
        float br = bih[j] + bhh[j];
        float bz = bih[H + j] + bhh[H + j];
        float bi = bih[2 * H + j], bh = bhh[2 * H + j];
#pragma unroll
        for (int m = 0; m < 4; ++m) {
            int node = nb + q * 4 + m;  // C/D: row = quad*4 + reg, col = lane&15
            float r = sigm_(acc[ct][m] + br);
            float z = sigm_(acc[2 + ct][m] + bz);
            float ng = tanh_(acc[4 + ct][m] + bi + r * (acc[6 + ct][m] + bh));
            float hj = (float)Xc1[(size_t)node * 64 + 32 + j];
            float o = fmaxf((1.f - z) * ng + z * hj, 0.f);
            if (node < NN) Hh[(size_t)node * 32 + j] = (half_t)o;
        }
    }
}

// ---------- K6: GRU layer2 + log_softmax via MFMA + shfl reduce, no LDS ----------
__global__ __launch_bounds__(256) void k6m(const half_t* __restrict__ Xc2,
                                           const half8* __restrict__ W2sw,
                                           const float* __restrict__ bih,
                                           const float* __restrict__ bhh,
                                           float* __restrict__ out) {
    int tid = threadIdx.x;
    int wave = tid >> 6, lane = tid & 63;
    int m16 = lane & 15, q = lane >> 4;
    int nb = blockIdx.x * 64 + wave * 16;
    const half8* xr = (const half8*)(Xc2 + (size_t)(nb + m16) * 96);
    half8 a0 = xr[q], a1 = xr[4 + q], a2 = xr[8 + q];
    f32x4 acc[12];
#pragma unroll
    for (int ct = 0; ct < 12; ++ct) acc[ct] = (f32x4){0.f, 0.f, 0.f, 0.f};
#pragma unroll
    for (int ct = 0; ct < 12; ++ct) {
        acc[ct] = __builtin_amdgcn_mfma_f32_16x16x32_f16(a0, W2sw[ct * 64 + lane], acc[ct], 0, 0, 0);
        acc[ct] = __builtin_amdgcn_mfma_f32_16x16x32_f16(a1, W2sw[(12 + ct) * 64 + lane], acc[ct], 0, 0, 0);
        acc[ct] = __builtin_amdgcn_mfma_f32_16x16x32_f16(a2, W2sw[(24 + ct) * 64 + lane], acc[ct], 0, 0, 0);
    }
    float v[3][4];
#pragma unroll
    for (int ct = 0; ct < 3; ++ct) {
        int j = ct * 16 + m16;
        int jc = (j < NC) ? j : (NC - 1);  // clamp (lanes with j>=40 produce unused values)
        float br = bih[jc] + bhh[jc];
        float bz = bih[NC + jc] + bhh[NC + jc];
        float bi = bih[2 * NC + jc], bh = bhh[2 * NC + jc];
#pragma unroll
        for (int m = 0; m < 4; ++m) {
            int node = nb + q * 4 + m;
            float r = sigm_(acc[ct][m] + br);
            float z = sigm_(acc[3 + ct][m] + bz);
            float ng = tanh_(acc[6 + ct][m] + bi + r * (acc[9 + ct][m] + bh));
            float hj = (float)Xc2[(size_t)node * 96 + 32 + jc];
            v[ct][m] = (1.f - z) * ng + z * hj;
        }
    }
    bool v2ok = (m16 < 8);  // ct=2 covers j=32..39 only for m16<8
#pragma unroll
    for (int m = 0; m < 4; ++m) {
        float mx = fmaxf(v[0][m], v[1][m]);
        if (v2ok) mx = fmaxf(mx, v[2][m]);
#pragma unroll
        for (int d = 1; d < 16; d <<= 1) mx = fmaxf(mx, __shfl_xor(mx, d));
        float se = __expf(v[0][m] - mx) + __expf(v[1][m] - mx) +
                   (v2ok ? __expf(v[2][m] - mx) : 0.f);
#pragma unroll
        for (int d = 1; d < 16; d <<= 1) se += __shfl_xor(se, d);
        float ls = mx + __logf(se);
        int node = nb + q * 4 + m;
        if (node < NN) {
            out[(size_t)node * NC + m16] = v[0][m] - ls;
            out[(size_t)node * NC + 16 + m16] = v[1][m] - ls;
            if (v2ok) out[(size_t)node * NC + 32 + m16] = v[2][m] - ls;
        }
    }
}

extern "C" void kernel_launch(void* const* d_in, const int* in_sizes, int n_in,
                              void* d_out, int out_size, void* d_ws, size_t ws_size,
                              hipStream_t stream) {
    const float* x = (const float*)d_in[0];
    const int* ei = (const int*)d_in[1];
    const float* ew = (const float*)d_in[2];
    const float* W1p = (const float*)d_in[3];
    const float* W1m = (const float*)d_in[4];
    const float* g1wih = (const float*)d_in[5];
    const float* g1whh = (const float*)d_in[6];
    const float* g1bih = (const float*)d_in[7];
    const float* g1bhh = (const float*)d_in[8];
    const float* W2p = (const float*)d_in[9];
    const float* W2m = (const float*)d_in[10];
    const float* g2wih = (const float*)d_in[11];
    const float* g2whh = (const float*)d_in[12];
    const float* g2bih = (const float*)d_in[13];
    const float* g2bhh = (const float*)d_in[14];
    float* ws = (float*)d_ws;

    // workspace layout (float indices), ~44 MB total (round-8 proven layout):
    half_t* Xc = (half_t*)ws;                 // [NP][64] layer1 / [NP][96] layer2 fp16 activations (4,801,536 f)
    half_t* Hh = (half_t*)(ws + 4801536);     // [NP][32] fp16 hrelu gather table (1,600,512 f)
    int2* rec = (int2*)ws;                    // CSR-build scratch (4,415,488 f) — dead before k1, overlays Xc
    int2* evs = (int2*)(ws + 6402048);        // 196*CAP sorted records (4,415,488 f)
    int* ofs = (int*)(ws + 10817536);         // 100,000
    int* ocn = (int*)(ws + 10917536);         // 100,000
    int* gcur = (int*)(ws + 11017536);        // 196 (+pad)
    half_t* W1sw = (half_t*)(ws + 11017792);  // 8,192 halves (4,096 f)
    half_t* W2sw = W1sw + 8192;               // 18,432 halves (9,216 f)
    float* M2 = ws + 11031104;                // 4,800 f: stage-1 fold W2m @ wih2^T
    float* out = (float*)d_out;

    // ---- CSR build (shared by both layers) ----
    hipMemsetAsync(gcur, 0, NBK * sizeof(int), stream);
    kA_bucket<<<(NE + EPB - 1) / EPB, 256, 0, stream>>>(ei, ew, gcur, (long long*)rec);
    kB_sort<<<NBK, 256, 0, stream>>>(gcur, rec, evs, ofs, ocn);
    k_wpre<<<(NC * 3 * NC + 255) / 256, 256, 0, stream>>>(W2m, g2wih, M2);
    k_wc<<<(8192 + 18432 + 255) / 256, 256, 0, stream>>>(
        W1m, g1wih, W2p, M2, g1whh, g2whh, W1sw, W2sw);

    // ---- layer 1 ----
    k1_proj<<<NN / 8, 256, 0, stream>>>(x, W1p, Xc);
    k_aggh<<<(NN * 4 + 255) / 256, 256, 0, stream>>>(ofs, ocn, evs, Xc + 32, 8, Xc, 64);
    k3m<<<NP / 64, 256, 0, stream>>>(Xc, (const half8*)W1sw, g1bih, g1bhh, Hh);

    // ---- layer 2 ----
    k4_proj2<<<NN / 8, 320, 0, stream>>>(Hh, W2p, Xc);
    k_aggh<<<(NN * 4 + 255) / 256, 256, 0, stream>>>(ofs, ocn, evs, Hh, 4, Xc, 96);
    k6m<<<NP / 64, 256, 0, stream>>>(Xc, (const half8*)W2sw, g2bih, g2bhh, out);
}